// Round 8
// baseline (420.942 us; speedup 1.0000x reference)
//
#include <hip/hip_runtime.h>
#include <math.h>

// B=8, H=8, L=1024, E=512. Wave = 4 rows (ROLLED loop); block = 8 waves = 32 l's.
// corr = Re(IFFT(FFT(q)*conj(FFT(k)))) via z=q+ik packing; FFT512 = radix-8^3
// with two wave-private padded-LDS transposes (float2/b64, no block barriers).
// R8: DPP wave-max topk (no DS shfl), precomputed twiddle powers, b64 LDS
// scratch, q/k prefetch across passes. Keep R7's rolled loop + bf16 tile.

#define TOPK 6
#define LGKM0 asm volatile("s_waitcnt lgkmcnt(0)" ::: "memory")

__device__ __forceinline__ float2 cmul(float2 a, float2 b) {
  return make_float2(fmaf(a.x, b.x, -(a.y * b.y)), fmaf(a.x, b.y, a.y * b.x));
}
__device__ __forceinline__ float2 cadd(float2 a, float2 b) { return make_float2(a.x + b.x, a.y + b.y); }
__device__ __forceinline__ float2 csub(float2 a, float2 b) { return make_float2(a.x - b.x, a.y - b.y); }
__device__ __forceinline__ float2 mnegi(float2 v) { return make_float2(v.y, -v.x); }  // * (-i)

__device__ __forceinline__ unsigned bf16rne(float x) {  // f32 -> bf16 bits (RNE)
  unsigned t = __float_as_uint(x);
  return (t + 0x7FFFu + ((t >> 16) & 1u)) >> 16;
}

// wave64 max-reduce entirely on the VALU pipe (DPP), result uniform (SGPR).
__device__ __forceinline__ unsigned wave_umax64(unsigned x) {
#define DPPMAX(ctrl)                                                          \
  {                                                                           \
    unsigned t = (unsigned)__builtin_amdgcn_update_dpp(0, (int)x, ctrl, 0xf,  \
                                                       0xf, true);            \
    x = t > x ? t : x;                                                        \
  }
  DPPMAX(0x111)  // row_shr:1
  DPPMAX(0x112)  // row_shr:2
  DPPMAX(0x114)  // row_shr:4
  DPPMAX(0x118)  // row_shr:8
  DPPMAX(0x142)  // row_bcast:15
  DPPMAX(0x143)  // row_bcast:31
#undef DPPMAX
  return (unsigned)__builtin_amdgcn_readlane((int)x, 63);
}

// out[r] = sum_m in[m] * W8^{m*r}
__device__ __forceinline__ void radix8(float2 y[8]) {
  float2 p0 = cadd(y[0], y[4]), p1 = csub(y[0], y[4]);
  float2 p2 = cadd(y[2], y[6]), p3 = csub(y[2], y[6]);
  float2 q0 = cadd(y[1], y[5]), q1 = csub(y[1], y[5]);
  float2 q2 = cadd(y[3], y[7]), q3 = csub(y[3], y[7]);
  float2 mp3 = mnegi(p3), mq3 = mnegi(q3);
  float2 E0 = cadd(p0, p2), E2 = csub(p0, p2);
  float2 E1 = cadd(p1, mp3), E3 = csub(p1, mp3);
  float2 O0 = cadd(q0, q2), O2 = csub(q0, q2);
  float2 O1 = cadd(q1, mq3), O3 = csub(q1, mq3);
  const float RT = 0.70710678118654752440f;
  float2 T1 = make_float2(RT * (O1.x + O1.y), RT * (O1.y - O1.x));   // *W8^1
  float2 T2 = mnegi(O2);                                             // *W8^2
  float2 T3 = make_float2(RT * (O3.y - O3.x), -RT * (O3.x + O3.y));  // *W8^3
  y[0] = cadd(E0, O0); y[4] = csub(E0, O0);
  y[1] = cadd(E1, T1); y[5] = csub(E1, T1);
  y[2] = cadd(E2, T2); y[6] = csub(E2, T2);
  y[3] = cadd(E3, T3); y[7] = csub(E3, T3);
}

__device__ __forceinline__ void twiddle8p(float2 y[8], const float2 W[7]) {
#pragma unroll
  for (int r = 1; r < 8; ++r) y[r] = cmul(y[r], W[r - 1]);
}

// In: y[m] = x[64m + u]. Out: y[r] = X[(u>>3) + 8*(u&7) + 64*r].
// Z: 576-float2 wave-private LDS scratch (b64 ops, all phases ~baseline banks).
__device__ __forceinline__ void fft512t(float2 y[8], float2* __restrict__ Z,
                                        int u, const float2 W1[7],
                                        const float2 W2[7]) {
  const int f0 = u >> 3, n0 = u & 7;
  radix8(y);
  twiddle8p(y, W1);
#pragma unroll
  for (int r = 0; r < 8; ++r) Z[72 * r + u] = y[r];
  LGKM0;
#pragma unroll
  for (int j = 0; j < 8; ++j) y[j] = Z[72 * f0 + 8 * j + n0];
  radix8(y);
  twiddle8p(y, W2);
  LGKM0;
#pragma unroll
  for (int g = 0; g < 8; ++g) Z[72 * f0 + 8 * g + (n0 ^ g)] = y[g];
  LGKM0;
#pragma unroll
  for (int j = 0; j < 8; ++j) y[j] = Z[72 * f0 + 8 * n0 + (j ^ n0)];
  radix8(y);
}

__global__ __launch_bounds__(512, 4) void autoagg_kernel(
    const float* __restrict__ q, const float* __restrict__ kk,
    const float* __restrict__ v, float* __restrict__ outV,
    float* __restrict__ outC) {
  __shared__ float2 Zall[8 * 576];           // 36864 B: per-wave FFT scratch
  __shared__ unsigned short tile[512 * 36];  // 36864 B: bf16 corrT tile (e x l)
  const int tid = threadIdx.x;
  const int u = tid & 63;
  const int w = tid >> 6;
  const int bid = blockIdx.x;
  float2* Zw = Zall + w * 576;
  float* zf = (float*)Zw;  // raw-float view for the V transpose

  const int f0 = u >> 3, n0 = u & 7;
  const int base = f0 + (n0 << 3);  // corr index of reg r is base + 64r

  const float N2PI = -6.28318530717958647692f;
  float s_, c_;
  __sincosf(N2PI * (float)u * (1.f / 512.f), &s_, &c_);
  const float2 w512u = make_float2(c_, s_);
  __sincosf(N2PI * (float)n0 * (1.f / 64.f), &s_, &c_);
  const float2 w64n0 = make_float2(c_, s_);
  float2 W1[7], W2[7];
  {
    float2 wp = w512u; W1[0] = wp;
#pragma unroll
    for (int r = 1; r < 7; ++r) { wp = cmul(wp, w512u); W1[r] = wp; }
    wp = w64n0; W2[0] = wp;
#pragma unroll
    for (int r = 1; r < 7; ++r) { wp = cmul(wp, w64n0); W2[r] = wp; }
  }

  const int bid5 = bid << 5;
  // prefetch pass 0's q/k
  float2 pf[8];
  {
    const float* qrow = q + (size_t)(bid5 + w) * 512;
    const float* krow = kk + (size_t)(bid5 + w) * 512;
#pragma unroll
    for (int m = 0; m < 8; ++m)
      pf[m] = make_float2(qrow[u + (m << 6)], krow[u + (m << 6)]);
  }

#pragma unroll 1
  for (int p = 0; p < 4; ++p) {   // ROLLED: keep code within L1I
    const int rowU = __builtin_amdgcn_readfirstlane(bid5 + (p << 3) + w);
    const float* vrow = v + (size_t)rowU * 512;

    float2 y[8];
#pragma unroll
    for (int m = 0; m < 8; ++m) y[m] = pf[m];
    if (p < 3) {  // prefetch next pass under this pass's compute
      const float* qn = q + (size_t)(rowU + 8) * 512;
      const float* kn = kk + (size_t)(rowU + 8) * 512;
#pragma unroll
      for (int m = 0; m < 8; ++m)
        pf[m] = make_float2(qn[u + (m << 6)], kn[u + (m << 6)]);
    }

    fft512t(y, Zw, u, W1, W2);  // Z at index (u>>3)+8(u&7)+64r

    LGKM0;
#pragma unroll
    for (int r = 0; r < 8; ++r)  // store Z at sigma3(f)=72(f>>6)+8((f>>3)&7)+(f&7)
      Zw[72 * r + (n0 << 3) + f0] = y[r];
    LGKM0;
    // Hermitian separation + pointwise product
    const float SCL = 1.f / 2048.f;
#pragma unroll
    for (int m = 0; m < 8; ++m) {
      int fB = (512 - ((m << 6) | u)) & 511;
      int sB = 72 * (fB >> 6) + (((fB >> 3) & 7) << 3) + (fB & 7);
      float2 A = Zw[72 * m + (f0 << 3) + n0];
      float2 Bv = Zw[sB];
      float sx = A.x + Bv.x, sy = A.y - Bv.y;   // 2Q
      float dx = A.x - Bv.x, dy = A.y + Bv.y;   // 2iK
      y[m] = make_float2((sx * dy - sy * dx) * SCL,
                         -fmaf(sx, dx, sy * dy) * SCL);
    }

    fft512t(y, Zw, u, W1, W2);  // corr[base+64r] = y[r].x

    // ---- persist corr into bf16 tile: tile[e][l-col], col = 8p + w
    const int col = (p << 3) | w;
#pragma unroll
    for (int r = 0; r < 8; ++r)
      tile[(base + (r << 6)) * 36 + col] = (unsigned short)bf16rne(y[r].x);

    // ---- top-6: packed key = (monotone value bits & ~0x1FF) | (511 - idx)
    unsigned key[8];
#pragma unroll
    for (int r = 0; r < 8; ++r) {
      unsigned bb = __float_as_uint(y[r].x);
      unsigned sgn = (unsigned)((int)bb >> 31);
      unsigned mono = bb ^ (sgn | 0x80000000u);
      key[r] = (mono & 0xFFFFFE00u) | (unsigned)(511 - (base + (r << 6)));
    }
    float w0 = 0.f, tw[TOPK]; int dly[TOPK];
#pragma unroll
    for (int it = 0; it < TOPK; ++it) {
      unsigned km = key[0];
#pragma unroll
      for (int i = 1; i < 8; ++i) km = key[i] > km ? key[i] : km;
      unsigned kmax = wave_umax64(km);  // uniform
      unsigned mb = kmax & 0xFFFFFE00u;
      unsigned vb = (mb & 0x80000000u) ? (mb ^ 0x80000000u) : ~mb;
      float val = __uint_as_float(vb);
      if (it == 0) w0 = val;
      tw[it] = __expf(val - w0);
      dly[it] = 511 - (int)(kmax & 0x1FFu);
#pragma unroll
      for (int i = 0; i < 8; ++i) if (key[i] == kmax) key[i] = 0u;
    }
    float ssum = 0.f;
#pragma unroll
    for (int it = 0; it < TOPK; ++it) ssum += tw[it];
    const float inv = 1.f / ssum;

    // ---- V[t] = sum_k w_k * v[(t + d_k) & 511], t = base + 64i (reg layout)
    float V[8] = {0.f, 0.f, 0.f, 0.f, 0.f, 0.f, 0.f, 0.f};
#pragma unroll
    for (int it = 0; it < TOPK; ++it) {
      const float twk = tw[it] * inv;
      const int d = dly[it];
#pragma unroll
      for (int i = 0; i < 8; ++i)
        V[i] = fmaf(twk, vrow[(base + (i << 6) + d) & 511], V[i]);
    }

    // ---- transpose V through wave scratch -> contiguous float4 stores
    LGKM0;
#pragma unroll
    for (int i = 0; i < 8; ++i)          // t = base+64i -> A = 76i + 9*n0 + f0
      zf[76 * i + 9 * n0 + f0] = V[i];
    LGKM0;
    float vt[8];
#pragma unroll
    for (int j = 0; j < 8; ++j)          // t = 8u+j -> A = 76*f0 + 9*n0 + j
      vt[j] = zf[76 * f0 + 9 * n0 + j];
    LGKM0;
    float4* ov = (float4*)(outV + (size_t)rowU * 512 + (u << 3));
    ov[0] = make_float4(vt[0], vt[1], vt[2], vt[3]);
    ov[1] = make_float4(vt[4], vt[5], vt[6], vt[7]);
  }

  // ---- epilogue: tile (bf16) -> outC[b][e][h][l], full 128B lines
  __syncthreads();
  const int b9 = bid >> 8;
  const int h9 = (bid >> 5) & 7;
  const int l0 = (bid & 31) << 5;
#pragma unroll
  for (int round = 0; round < 8; ++round) {
    int e = (round << 6) + (tid >> 3);   // 0..511
    int lq = (tid & 7) << 2;             // l offset 0,4,...,28
    uint2 tt = *(const uint2*)(tile + e * 36 + lq);  // 8B-aligned (72e+8k)
    float4 tv = make_float4(__uint_as_float(tt.x << 16),
                            __uint_as_float(tt.x & 0xFFFF0000u),
                            __uint_as_float(tt.y << 16),
                            __uint_as_float(tt.y & 0xFFFF0000u));
    *(float4*)(outC + (((size_t)b9 * 512 + e) * 8 + h9) * 1024 + l0 + lq) = tv;
  }
}

extern "C" void kernel_launch(void* const* d_in, const int* in_sizes, int n_in,
                              void* d_out, int out_size, void* d_ws, size_t ws_size,
                              hipStream_t stream) {
  const float* q = (const float*)d_in[0];
  const float* k = (const float*)d_in[1];
  const float* v = (const float*)d_in[2];
  float* outV = (float*)d_out;
  float* outC = (float*)d_out + (size_t)8 * 8 * 1024 * 512;
  dim3 grid(65536 / 32), block(512);
  hipLaunchKernelGGL(autoagg_kernel, grid, block, 0, stream, q, k, v, outV, outC);
}

// Round 9
// 230.335 us; speedup vs baseline: 1.8275x; 1.8275x over previous
//
#include <hip/hip_runtime.h>
#include <math.h>

// B=8, H=8, L=1024, E=512. Wave = 4 rows (ROLLED loop); block = 8 waves = 32 l's.
// corr = Re(IFFT(FFT(q)*conj(FFT(k)))) via z=q+ik packing; FFT512 = radix-8^3
// with two wave-private padded-LDS transposes (no block barriers in FFT).
// R9 = R7 + DPP wave-max topk ONLY. R8's prefetch + twiddle-precompute pushed
// live regs past the allocator's 64-VGPR pin -> scratch spill (FETCH/WRITE
// +400MB). Rule: keep peak live state under 64 VGPRs.

#define TOPK 6
#define LGKM0 asm volatile("s_waitcnt lgkmcnt(0)" ::: "memory")

__device__ __forceinline__ float2 cmul(float2 a, float2 b) {
  return make_float2(fmaf(a.x, b.x, -(a.y * b.y)), fmaf(a.x, b.y, a.y * b.x));
}
__device__ __forceinline__ float2 cadd(float2 a, float2 b) { return make_float2(a.x + b.x, a.y + b.y); }
__device__ __forceinline__ float2 csub(float2 a, float2 b) { return make_float2(a.x - b.x, a.y - b.y); }
__device__ __forceinline__ float2 mnegi(float2 v) { return make_float2(v.y, -v.x); }  // * (-i)

__device__ __forceinline__ unsigned bf16rne(float x) {  // f32 -> bf16 bits (RNE)
  unsigned t = __float_as_uint(x);
  return (t + 0x7FFFu + ((t >> 16) & 1u)) >> 16;
}

// wave64 max-reduce on the VALU pipe (canonical GCN DPP reduction sequence);
// result uniform via readlane(63). Proven correct in R8.
__device__ __forceinline__ unsigned wave_umax64(unsigned x) {
#define DPPMAX(ctrl)                                                          \
  {                                                                           \
    unsigned t = (unsigned)__builtin_amdgcn_update_dpp(0, (int)x, ctrl, 0xf,  \
                                                       0xf, true);            \
    x = t > x ? t : x;                                                        \
  }
  DPPMAX(0x111)  // row_shr:1
  DPPMAX(0x112)  // row_shr:2
  DPPMAX(0x114)  // row_shr:4
  DPPMAX(0x118)  // row_shr:8
  DPPMAX(0x142)  // row_bcast:15
  DPPMAX(0x143)  // row_bcast:31
#undef DPPMAX
  return (unsigned)__builtin_amdgcn_readlane((int)x, 63);
}

// out[r] = sum_m in[m] * W8^{m*r}
__device__ __forceinline__ void radix8(float2 y[8]) {
  float2 p0 = cadd(y[0], y[4]), p1 = csub(y[0], y[4]);
  float2 p2 = cadd(y[2], y[6]), p3 = csub(y[2], y[6]);
  float2 q0 = cadd(y[1], y[5]), q1 = csub(y[1], y[5]);
  float2 q2 = cadd(y[3], y[7]), q3 = csub(y[3], y[7]);
  float2 mp3 = mnegi(p3), mq3 = mnegi(q3);
  float2 E0 = cadd(p0, p2), E2 = csub(p0, p2);
  float2 E1 = cadd(p1, mp3), E3 = csub(p1, mp3);
  float2 O0 = cadd(q0, q2), O2 = csub(q0, q2);
  float2 O1 = cadd(q1, mq3), O3 = csub(q1, mq3);
  const float RT = 0.70710678118654752440f;
  float2 T1 = make_float2(RT * (O1.x + O1.y), RT * (O1.y - O1.x));   // *W8^1
  float2 T2 = mnegi(O2);                                             // *W8^2
  float2 T3 = make_float2(RT * (O3.y - O3.x), -RT * (O3.x + O3.y));  // *W8^3
  y[0] = cadd(E0, O0); y[4] = csub(E0, O0);
  y[1] = cadd(E1, T1); y[5] = csub(E1, T1);
  y[2] = cadd(E2, T2); y[6] = csub(E2, T2);
  y[3] = cadd(E3, T3); y[7] = csub(E3, T3);
}

__device__ __forceinline__ void twiddle8(float2 y[8], float2 w) {
  float2 wp = w;
  y[1] = cmul(y[1], wp);
  wp = cmul(wp, w); y[2] = cmul(y[2], wp);
  wp = cmul(wp, w); y[3] = cmul(y[3], wp);
  wp = cmul(wp, w); y[4] = cmul(y[4], wp);
  wp = cmul(wp, w); y[5] = cmul(y[5], wp);
  wp = cmul(wp, w); y[6] = cmul(y[6], wp);
  wp = cmul(wp, w); y[7] = cmul(y[7], wp);
}

// In: y[m] = x[64m + u]. Out: y[r] = X[(u>>3) + 8*(u&7) + 64*r].
__device__ __forceinline__ void fft512t(float2 y[8], float* zx, float* zy,
                                        int u, float2 w512u, float2 w64n0) {
  const int f0 = u >> 3, n0 = u & 7;
  radix8(y);
  twiddle8(y, w512u);
#pragma unroll
  for (int r = 0; r < 8; ++r) { int s = 72 * r + u; zx[s] = y[r].x; zy[s] = y[r].y; }
  LGKM0;
#pragma unroll
  for (int j = 0; j < 8; ++j) {
    int s = 72 * f0 + 8 * j + n0;
    y[j] = make_float2(zx[s], zy[s]);
  }
  radix8(y);
  twiddle8(y, w64n0);
  LGKM0;
#pragma unroll
  for (int g = 0; g < 8; ++g) {
    int s = 72 * f0 + 8 * g + (n0 ^ g);
    zx[s] = y[g].x; zy[s] = y[g].y;
  }
  LGKM0;
#pragma unroll
  for (int j = 0; j < 8; ++j) {
    int s = 72 * f0 + 8 * n0 + (j ^ n0);
    y[j] = make_float2(zx[s], zy[s]);
  }
  radix8(y);
}

__global__ __launch_bounds__(512, 4) void autoagg_kernel(
    const float* __restrict__ q, const float* __restrict__ kk,
    const float* __restrict__ v, float* __restrict__ outV,
    float* __restrict__ outC) {
  __shared__ float zscr[8 * 1152];           // 36864 B: per-wave FFT scratch
  __shared__ unsigned short tile[512 * 36];  // 36864 B: bf16 corrT tile (e x l)
  const int tid = threadIdx.x;
  const int u = tid & 63;
  const int w = tid >> 6;
  const int bid = blockIdx.x;
  float* zx = zscr + w * 1152;
  float* zy = zx + 576;

  const int f0 = u >> 3, n0 = u & 7;
  const int base = f0 + (n0 << 3);  // corr index of reg r is base + 64r

  const float N2PI = -6.28318530717958647692f;
  float s_, c_;
  __sincosf(N2PI * (float)u * (1.f / 512.f), &s_, &c_);
  const float2 w512u = make_float2(c_, s_);
  __sincosf(N2PI * (float)n0 * (1.f / 64.f), &s_, &c_);
  const float2 w64n0 = make_float2(c_, s_);

#pragma unroll 1
  for (int p = 0; p < 4; ++p) {   // ROLLED: keep code within L1I
    const int row = (bid << 5) + (p << 3) + w;
    const int rowU = __builtin_amdgcn_readfirstlane(row);
    const float* qrow = q + (size_t)rowU * 512;
    const float* krow = kk + (size_t)rowU * 512;
    const float* vrow = v + (size_t)rowU * 512;

    float2 y[8];
#pragma unroll
    for (int m = 0; m < 8; ++m)
      y[m] = make_float2(qrow[u + (m << 6)], krow[u + (m << 6)]);

    fft512t(y, zx, zy, u, w512u, w64n0);  // Z at index (u>>3)+8(u&7)+64r

    LGKM0;
#pragma unroll
    for (int r = 0; r < 8; ++r) {  // store Z at sigma3(f)=72(f>>6)+8((f>>3)&7)+(f&7)
      int s = 72 * r + (n0 << 3) + f0;
      zx[s] = y[r].x; zy[s] = y[r].y;
    }
    LGKM0;
    // Hermitian separation + pointwise product
    const float SCL = 1.f / 2048.f;
#pragma unroll
    for (int m = 0; m < 8; ++m) {
      int fA = (m << 6) | u;
      int fB = (512 - fA) & 511;
      int sA = 72 * m + (f0 << 3) + n0;
      int sB = 72 * (fB >> 6) + (((fB >> 3) & 7) << 3) + (fB & 7);
      float Ax = zx[sA], Ay = zy[sA];
      float Bx = zx[sB], By = zy[sB];
      float sx = Ax + Bx, sy = Ay - By;   // 2Q
      float dx = Ax - Bx, dy = Ay + By;   // 2iK
      y[m] = make_float2((sx * dy - sy * dx) * SCL,
                         -fmaf(sx, dx, sy * dy) * SCL);
    }

    fft512t(y, zx, zy, u, w512u, w64n0);  // corr[base+64r] = y[r].x

    // ---- persist corr into bf16 tile: tile[e][l-col], col = 8p + w
    const int col = (p << 3) | w;
#pragma unroll
    for (int r = 0; r < 8; ++r)
      tile[(base + (r << 6)) * 36 + col] = (unsigned short)bf16rne(y[r].x);

    // ---- top-6: packed key = (monotone value bits & ~0x1FF) | (511 - idx)
    unsigned key[8];
#pragma unroll
    for (int r = 0; r < 8; ++r) {
      unsigned bb = __float_as_uint(y[r].x);
      unsigned sgn = (unsigned)((int)bb >> 31);
      unsigned mono = bb ^ (sgn | 0x80000000u);
      key[r] = (mono & 0xFFFFFE00u) | (unsigned)(511 - (base + (r << 6)));
    }
    float w0 = 0.f, tw[TOPK]; int dly[TOPK];
#pragma unroll
    for (int it = 0; it < TOPK; ++it) {
      unsigned km = key[0];
#pragma unroll
      for (int i = 1; i < 8; ++i) km = key[i] > km ? key[i] : km;
      unsigned kmax = wave_umax64(km);  // uniform
      unsigned mb = kmax & 0xFFFFFE00u;
      unsigned vb = (mb & 0x80000000u) ? (mb ^ 0x80000000u) : ~mb;
      float val = __uint_as_float(vb);
      if (it == 0) w0 = val;
      tw[it] = __expf(val - w0);
      dly[it] = 511 - (int)(kmax & 0x1FFu);
#pragma unroll
      for (int i = 0; i < 8; ++i) if (key[i] == kmax) key[i] = 0u;
    }
    float ssum = 0.f;
#pragma unroll
    for (int it = 0; it < TOPK; ++it) ssum += tw[it];
    const float inv = 1.f / ssum;

    // ---- V[t] = sum_k w_k * v[(t + d_k) & 511], t = base + 64i (reg layout)
    float V[8] = {0.f, 0.f, 0.f, 0.f, 0.f, 0.f, 0.f, 0.f};
#pragma unroll
    for (int it = 0; it < TOPK; ++it) {
      const float twk = tw[it] * inv;
      const int d = dly[it];
#pragma unroll
      for (int i = 0; i < 8; ++i)
        V[i] = fmaf(twk, vrow[(base + (i << 6) + d) & 511], V[i]);
    }

    // ---- transpose V through wave scratch -> contiguous float4 stores
    LGKM0;
#pragma unroll
    for (int i = 0; i < 8; ++i)          // t = base+64i -> A = 76i + 9*n0 + f0
      zx[76 * i + 9 * n0 + f0] = V[i];
    LGKM0;
    float vt[8];
#pragma unroll
    for (int j = 0; j < 8; ++j)          // t = 8u+j -> A = 76*f0 + 9*n0 + j
      vt[j] = zx[76 * f0 + 9 * n0 + j];
    LGKM0;
    float4* ov = (float4*)(outV + (size_t)rowU * 512 + (u << 3));
    ov[0] = make_float4(vt[0], vt[1], vt[2], vt[3]);
    ov[1] = make_float4(vt[4], vt[5], vt[6], vt[7]);
  }

  // ---- epilogue: tile (bf16) -> outC[b][e][h][l], full 128B lines
  __syncthreads();
  const int b9 = bid >> 8;
  const int h9 = (bid >> 5) & 7;
  const int l0 = (bid & 31) << 5;
#pragma unroll
  for (int round = 0; round < 8; ++round) {
    int e = (round << 6) + (tid >> 3);   // 0..511
    int lq = (tid & 7) << 2;             // l offset 0,4,...,28
    const unsigned short* tr = tile + e * 36 + lq;
    float4 tv = make_float4(__uint_as_float((unsigned)tr[0] << 16),
                            __uint_as_float((unsigned)tr[1] << 16),
                            __uint_as_float((unsigned)tr[2] << 16),
                            __uint_as_float((unsigned)tr[3] << 16));
    *(float4*)(outC + (((size_t)b9 * 512 + e) * 8 + h9) * 1024 + l0 + lq) = tv;
  }
}

extern "C" void kernel_launch(void* const* d_in, const int* in_sizes, int n_in,
                              void* d_out, int out_size, void* d_ws, size_t ws_size,
                              hipStream_t stream) {
  const float* q = (const float*)d_in[0];
  const float* k = (const float*)d_in[1];
  const float* v = (const float*)d_in[2];
  float* outV = (float*)d_out;
  float* outC = (float*)d_out + (size_t)8 * 8 * 1024 * 512;
  dim3 grid(65536 / 32), block(512);
  hipLaunchKernelGGL(autoagg_kernel, grid, block, 0, stream, q, k, v, outV, outC);
}